// Round 1
// baseline (456.279 us; speedup 1.0000x reference)
//
#include <hip/hip_runtime.h>

typedef float f4 __attribute__((ext_vector_type(4)));
typedef float f2 __attribute__((ext_vector_type(2)));

#define Bsz  8192
#define Dsz  64
#define Hsz  128
#define Tsz  41
#define ROWS 32
#define NT   256

__device__ __forceinline__ float fast_tanh(float x) {
    float ax = __builtin_fabsf(x);
    float e  = __expf(-2.0f * ax);                       // v_exp based
    float r  = (1.0f - e) * __builtin_amdgcn_rcpf(1.0f + e);
    return __builtin_copysignf(r, x);
}

// swizzled word index for a [NROW][32] tile: row-major stride 32 words,
// 4-word column-blocks XOR-permuted by row bits -> kills write bank conflicts
__device__ __forceinline__ int swz(int row, int blk) {
    return (row << 5) + ((blk ^ ((row >> 2) & 7)) << 2);
}

__global__ __launch_bounds__(NT, 1)
void ode_euler_kernel(const float* __restrict__ z0, const float* __restrict__ t,
                      const float* __restrict__ W1, const float* __restrict__ b1,
                      const float* __restrict__ W2, const float* __restrict__ b2,
                      float* __restrict__ out)
{
    __shared__ float W1s[Dsz * Hsz];   // [d][j] row-major
    __shared__ float W2s[Hsz * Dsz];   // [k][d] row-major
    __shared__ float zS[Dsz * ROWS];   // transposed z tile: zS[d][r], swizzled
    __shared__ float aS[Hsz * ROWS];   // transposed activations: aS[j][r], swizzled
    __shared__ float ts[Tsz];

    const int tid = threadIdx.x;
    const int r0  = blockIdx.x * ROWS;
    const int tr  = tid >> 5;   // 0..7  -> rows 4*tr..4*tr+3
    const int tj  = tid & 31;   // layer1: cols 4*tj..+3 ; layer2: cols 2*tj..+1

    // ---- stage weights (coalesced float4) ----
    {
        const f4* w1v = (const f4*)W1; f4* w1s = (f4*)W1s;
        #pragma unroll
        for (int i = 0; i < (Dsz * Hsz / 4) / NT; ++i) w1s[tid + i * NT] = w1v[tid + i * NT];
        const f4* w2v = (const f4*)W2; f4* w2s = (f4*)W2s;
        #pragma unroll
        for (int i = 0; i < (Hsz * Dsz / 4) / NT; ++i) w2s[tid + i * NT] = w2v[tid + i * NT];
        if (tid < Tsz) ts[tid] = t[tid];
    }

    // biases into registers (fixed per-thread columns)
    f4 b1r; f2 b2r;
    #pragma unroll
    for (int u = 0; u < 4; ++u) b1r[u] = b1[(tj << 2) + u];
    b2r[0] = b2[(tj << 1) + 0];
    b2r[1] = b2[(tj << 1) + 1];

    // ---- stage z tile, transposed + swizzled ----
    for (int i = tid; i < ROWS * Dsz; i += NT) {
        int r = i >> 6, d = i & (Dsz - 1);
        zS[swz(d, r >> 2) + (r & 3)] = z0[(r0 + r) * Dsz + d];
    }
    __syncthreads();

    const int n_steps = (int)ceilf(fabsf(ts[1] - ts[0]) / 0.05f);   // = 2

    for (int iv = 0; iv < Tsz - 1; ++iv) {
        float h = (ts[iv + 1] - ts[iv]) / (float)n_steps;
        for (int s = 0; s < n_steps; ++s) {
            // ---------- layer 1: a = tanh(z @ W1 + b1), 4 rows x 4 cols ----------
            f4 a0 = b1r, a1 = b1r, a2 = b1r, a3 = b1r;
            #pragma unroll 8
            for (int d = 0; d < Dsz; ++d) {
                f4 z4 = *(const f4*)&zS[swz(d, tr)];                 // rows 4tr..+3 (bcast)
                f4 w4 = *(const f4*)&W1s[(d << 7) + (tj << 2)];      // cols 4tj..+3
                a0 += z4[0] * w4;
                a1 += z4[1] * w4;
                a2 += z4[2] * w4;
                a3 += z4[3] * w4;
            }
            #pragma unroll
            for (int u = 0; u < 4; ++u) {
                int j = (tj << 2) + u;
                f4 av;
                av[0] = fast_tanh(a0[u]);
                av[1] = fast_tanh(a1[u]);
                av[2] = fast_tanh(a2[u]);
                av[3] = fast_tanh(a3[u]);
                *(f4*)&aS[swz(j, tr)] = av;                          // swizzled write
            }
            __syncthreads();

            // ---------- layer 2: dz = a @ W2 + b2, 4 rows x 2 cols; z += h*dz ----------
            f4 c0 = { b2r[0], b2r[0], b2r[0], b2r[0] };
            f4 c1 = { b2r[1], b2r[1], b2r[1], b2r[1] };
            #pragma unroll 8
            for (int k = 0; k < Hsz; ++k) {
                f4 a4 = *(const f4*)&aS[swz(k, tr)];                 // rows 4tr..+3 (bcast)
                f2 w2 = *(const f2*)&W2s[(k << 6) + (tj << 1)];      // cols 2tj..+1
                c0 += a4 * w2[0];
                c1 += a4 * w2[1];
            }
            #pragma unroll
            for (int v = 0; v < 2; ++v) {
                int d2 = (tj << 1) + v;
                float* zp = &zS[swz(d2, tr)];
                f4 zo = *(const f4*)zp;
                f4 cc = v ? c1 : c0;
                zo += h * cc;
                *(f4*)zp = zo;
            }
            __syncthreads();
        }
    }

    // ---- write result ----
    for (int i = tid; i < ROWS * Dsz; i += NT) {
        int r = i >> 6, d = i & (Dsz - 1);
        out[(r0 + r) * Dsz + d] = zS[swz(d, r >> 2) + (r & 3)];
    }
}

extern "C" void kernel_launch(void* const* d_in, const int* in_sizes, int n_in,
                              void* d_out, int out_size, void* d_ws, size_t ws_size,
                              hipStream_t stream) {
    const float* z0 = (const float*)d_in[0];
    const float* t  = (const float*)d_in[1];
    const float* W1 = (const float*)d_in[2];
    const float* b1 = (const float*)d_in[3];
    const float* W2 = (const float*)d_in[4];
    const float* b2 = (const float*)d_in[5];
    float* out = (float*)d_out;
    (void)in_sizes; (void)n_in; (void)out_size; (void)d_ws; (void)ws_size;

    ode_euler_kernel<<<dim3(Bsz / ROWS), dim3(NT), 0, stream>>>(z0, t, W1, b1, W2, b2, out);
}

// Round 2
// 148.802 us; speedup vs baseline: 3.0663x; 3.0663x over previous
//
#include <hip/hip_runtime.h>

typedef float  f32x4  __attribute__((ext_vector_type(4)));
typedef float  f4     __attribute__((ext_vector_type(4)));
typedef short  bf16x8 __attribute__((ext_vector_type(8)));
typedef unsigned u32x4 __attribute__((ext_vector_type(4)));

#define Bsz  8192
#define Dsz  64
#define Hsz  128
#define Tsz  41
#define ROWS 16
#define NT   256
#define ZLD  68   // zS row stride (floats): 2-way-max bank aliasing, 16B aligned

__device__ __forceinline__ unsigned bf16_rne(float x) {
    unsigned u = __float_as_uint(x);
    return (u + 0x7FFFu + ((u >> 16) & 1u)) >> 16;
}
__device__ __forceinline__ float bf16f(unsigned h) { return __uint_as_float(h << 16); }

__device__ __forceinline__ float fast_tanh(float x) {
    float ax = __builtin_fabsf(x);
    float e  = __expf(-2.0f * ax);
    float r  = (1.0f - e) * __builtin_amdgcn_rcpf(1.0f + e);
    return __builtin_copysignf(r, x);
}

union Frag { bf16x8 f; unsigned u[4]; };

// split 8 f32 -> hi/lo bf16 fragments (elem i in position i; 2 bf16/dword, even elem low)
__device__ __forceinline__ void split8(const float* x, Frag& hi, Frag& lo) {
    #pragma unroll
    for (int p = 0; p < 4; ++p) {
        unsigned h0 = bf16_rne(x[2*p]), h1 = bf16_rne(x[2*p+1]);
        float l0 = x[2*p]   - bf16f(h0);
        float l1 = x[2*p+1] - bf16f(h1);
        hi.u[p] = h0 | (h1 << 16);
        lo.u[p] = bf16_rne(l0) | (bf16_rne(l1) << 16);
    }
}

#define MFMA(a, b, c) __builtin_amdgcn_mfma_f32_16x16x32_bf16((a), (b), (c), 0, 0, 0)

__global__ __launch_bounds__(NT, 2)
void ode_mfma_kernel(const float* __restrict__ z0, const float* __restrict__ t,
                     const float* __restrict__ W1, const float* __restrict__ b1,
                     const float* __restrict__ W2, const float* __restrict__ b2,
                     float* __restrict__ out)
{
    __shared__ float    zS[ROWS * ZLD];    // f32 z master, [row][d] stride 68
    __shared__ unsigned aAd[ROWS * Hsz];   // activation: [row][k] dword = hi | lo<<16, XOR-swizzled
    __shared__ float    ts[Tsz];

    const int tid  = threadIdx.x;
    const int lane = tid & 63;
    const int w    = tid >> 6;   // wave 0..3: owns layer1 cols w*32..+32, layer2 cols w*16..+16
    const int g    = lane >> 4;  // 16-lane group
    const int c    = lane & 15;
    const int r0   = blockIdx.x * ROWS;

    if (tid < Tsz) ts[tid] = t[tid];
    {   // stage z tile (row-major, coalesced f4)
        int r = tid >> 4, d = (tid & 15) << 2;
        *(f4*)&zS[r * ZLD + d] = *(const f4*)&z0[(r0 + r) * Dsz + d];
    }

    // ---- loop-invariant weight B-fragments in registers (hi/lo split) ----
    // B layout assumed: lane holds B[kt*32 + 8*g + i][ncol], i=0..7, ncol = ntile*16 + c
    Frag w1h[2][2], w1l[2][2];   // [nt][kt]
    #pragma unroll
    for (int nt = 0; nt < 2; ++nt) {
        int n = w * 32 + nt * 16 + c;
        #pragma unroll
        for (int kt = 0; kt < 2; ++kt) {
            float tmp[8];
            #pragma unroll
            for (int i = 0; i < 8; ++i) tmp[i] = W1[(kt*32 + g*8 + i) * Hsz + n];
            split8(tmp, w1h[nt][kt], w1l[nt][kt]);
        }
    }
    Frag w2h[4], w2l[4];         // [kt]
    {
        int n = w * 16 + c;
        #pragma unroll
        for (int kt = 0; kt < 4; ++kt) {
            float tmp[8];
            #pragma unroll
            for (int i = 0; i < 8; ++i) tmp[i] = W2[(kt*32 + g*8 + i) * Dsz + n];
            split8(tmp, w2h[kt], w2l[kt]);
        }
    }
    const float b1r0 = b1[w*32 + c], b1r1 = b1[w*32 + 16 + c];
    const float b2r  = b2[w*16 + c];

    __syncthreads();

    const int n_steps = (int)ceilf(fabsf(ts[1] - ts[0]) * (1.0f / 0.05f));  // = 2

    for (int iv = 0; iv < Tsz - 1; ++iv) {
        const float h = (ts[iv + 1] - ts[iv]) / (float)n_steps;
        for (int s = 0; s < n_steps; ++s) {
            // ---- z -> A fragments (A row = c, k = kt*32 + 8g + i), hi/lo split
            Frag zh[2], zl[2];
            #pragma unroll
            for (int kt = 0; kt < 2; ++kt) {
                float tmp[8];
                *(f4*)&tmp[0] = *(const f4*)&zS[c * ZLD + kt*32 + g*8];
                *(f4*)&tmp[4] = *(const f4*)&zS[c * ZLD + kt*32 + g*8 + 4];
                split8(tmp, zh[kt], zl[kt]);
            }
            // ---- layer 1: a_pre = z @ W1 + b1 (3-product split-bf16), tanh, pack to LDS
            #pragma unroll
            for (int nt = 0; nt < 2; ++nt) {
                float bv = nt ? b1r1 : b1r0;
                f32x4 acc = {bv, bv, bv, bv};
                #pragma unroll
                for (int kt = 0; kt < 2; ++kt) {
                    acc = MFMA(zh[kt].f, w1h[nt][kt].f, acc);
                    acc = MFMA(zh[kt].f, w1l[nt][kt].f, acc);
                    acc = MFMA(zl[kt].f, w1h[nt][kt].f, acc);
                }
                int k = w*32 + nt*16 + c;            // activation column = layer2 k
                #pragma unroll
                for (int reg = 0; reg < 4; ++reg) {
                    int row = g*4 + reg;             // C row = 4*(lane>>4)+reg  [m89 verified]
                    float a = fast_tanh(acc[reg]);
                    unsigned hh = bf16_rne(a);
                    unsigned ll = bf16_rne(a - bf16f(hh));
                    int idx = (row * Hsz + k) ^ ((row & 7) << 2);   // 16B-granule XOR swizzle
                    aAd[idx] = hh | (ll << 16);
                }
            }
            __syncthreads();
            // ---- layer 2: dz = a @ W2 + b2
            f32x4 acc2 = {b2r, b2r, b2r, b2r};
            #pragma unroll
            for (int kt = 0; kt < 4; ++kt) {
                int i0 = (c * Hsz + kt*32 + g*8)     ^ ((c & 7) << 2);
                int i1 = (c * Hsz + kt*32 + g*8 + 4) ^ ((c & 7) << 2);
                u32x4 qa = *(const u32x4*)&aAd[i0];  // elems k0..k0+3 (hi|lo packed)
                u32x4 qb = *(const u32x4*)&aAd[i1];  // elems k0+4..k0+7
                Frag ah, al;
                ah.u[0] = (qa[0] & 0xFFFFu) | (qa[1] << 16);
                ah.u[1] = (qa[2] & 0xFFFFu) | (qa[3] << 16);
                ah.u[2] = (qb[0] & 0xFFFFu) | (qb[1] << 16);
                ah.u[3] = (qb[2] & 0xFFFFu) | (qb[3] << 16);
                al.u[0] = (qa[0] >> 16) | (qa[1] & 0xFFFF0000u);
                al.u[1] = (qa[2] >> 16) | (qa[3] & 0xFFFF0000u);
                al.u[2] = (qb[0] >> 16) | (qb[1] & 0xFFFF0000u);
                al.u[3] = (qb[2] >> 16) | (qb[3] & 0xFFFF0000u);
                acc2 = MFMA(ah.f, w2h[kt].f, acc2);
                acc2 = MFMA(ah.f, w2l[kt].f, acc2);
                acc2 = MFMA(al.f, w2h[kt].f, acc2);
            }
            // ---- z += h * dz  (wave owns cols w*16..+16; C row = g*4+reg)
            #pragma unroll
            for (int reg = 0; reg < 4; ++reg) {
                int r = g*4 + reg;
                zS[r * ZLD + w*16 + c] += h * acc2[reg];
            }
            __syncthreads();
        }
    }

    {   // epilogue
        int r = tid >> 4, d = (tid & 15) << 2;
        *(f4*)&out[(r0 + r) * Dsz + d] = *(const f4*)&zS[r * ZLD + d];
    }
}

extern "C" void kernel_launch(void* const* d_in, const int* in_sizes, int n_in,
                              void* d_out, int out_size, void* d_ws, size_t ws_size,
                              hipStream_t stream) {
    const float* z0 = (const float*)d_in[0];
    const float* t  = (const float*)d_in[1];
    const float* W1 = (const float*)d_in[2];
    const float* b1 = (const float*)d_in[3];
    const float* W2 = (const float*)d_in[4];
    const float* b2 = (const float*)d_in[5];
    float* out = (float*)d_out;
    (void)in_sizes; (void)n_in; (void)out_size; (void)d_ws; (void)ws_size;

    ode_mfma_kernel<<<dim3(Bsz / ROWS), dim3(NT), 0, stream>>>(z0, t, W1, b1, W2, b2, out);
}

// Round 3
// 94.066 us; speedup vs baseline: 4.8506x; 1.5819x over previous
//
#include <hip/hip_runtime.h>
#include <hip/hip_bf16.h>

typedef float  f32x4  __attribute__((ext_vector_type(4)));
typedef short  bf16x8 __attribute__((ext_vector_type(8)));

#define Bsz  8192
#define Dsz  64
#define Hsz  128
#define Tsz  41
#define ROWS 16
#define NT   256

#define MFMA(a,b,c) __builtin_amdgcn_mfma_f32_16x16x32_bf16((a),(b),(c),0,0,0)

__device__ __forceinline__ float fast_tanh(float x) {
    float ax = __builtin_fabsf(x);
    float e  = __expf(-2.0f * ax);
    float r  = (1.0f - e) * __builtin_amdgcn_rcpf(1.0f + e);
    return __builtin_copysignf(r, x);
}

__device__ __forceinline__ unsigned short bf2u(__hip_bfloat16 h) {
    union { __hip_bfloat16 b; unsigned short u; } v; v.b = h; return v.u;
}

union FragU { bf16x8 f; unsigned short h[8]; };

// split 8 f32 into hi/lo bf16 fragments (compiler-native casts -> v_cvt path)
__device__ __forceinline__ void split8(const float* x, bf16x8& hi, bf16x8& lo) {
    FragU H, L;
    #pragma unroll
    for (int i = 0; i < 8; ++i) {
        __hip_bfloat16 hb = __float2bfloat16(x[i]);
        H.h[i] = bf2u(hb);
        L.h[i] = bf2u(__float2bfloat16(x[i] - __bfloat162float(hb)));
    }
    hi = H.f; lo = L.f;
}

__device__ __forceinline__ bf16x8 ldb128(const unsigned short* base, int byteoff) {
    return *(const bf16x8*)((const char*)base + byteoff);
}
__device__ __forceinline__ void stb16(unsigned short* base, int byteoff, unsigned short v) {
    *(unsigned short*)((char*)base + byteoff) = v;
}

__global__ __launch_bounds__(NT, 2)
void ode_mfma3(const float* __restrict__ z0, const float* __restrict__ t,
               const float* __restrict__ W1, const float* __restrict__ b1,
               const float* __restrict__ W2, const float* __restrict__ b2,
               float* __restrict__ out)
{
    // bf16 H/L operand tiles, [row][k], byte-index XOR-swizzled by (row&7)<<4
    __shared__ __align__(16) unsigned short zHs[ROWS * 64],  zLs[ROWS * 64];   // z: 128 B/row
    __shared__ __align__(16) unsigned short aHs[ROWS * 128], aLs[ROWS * 128];  // act: 256 B/row
    __shared__ float ts[Tsz];

    const int tid  = threadIdx.x;
    const int lane = tid & 63;
    const int w    = tid >> 6;   // wave: layer1 cols w*32..+32, layer2 cols w*16..+16
    const int g    = lane >> 4;
    const int c    = lane & 15;
    const int r0   = blockIdx.x * ROWS;

    if (tid < Tsz) ts[tid] = t[tid];

    // ---- z master in registers: zreg[reg] = z[row=4g+reg][d=w*16+c] ----
    float zreg[4];
    #pragma unroll
    for (int reg = 0; reg < 4; ++reg)
        zreg[reg] = z0[(r0 + 4*g + reg) * Dsz + (w*16 + c)];

    // ---- loop-invariant weight B-fragments (hi/lo split), layout per m89 ----
    bf16x8 w1h[2][2], w1l[2][2];
    #pragma unroll
    for (int nt = 0; nt < 2; ++nt) {
        const int n = w*32 + nt*16 + c;
        #pragma unroll
        for (int kt = 0; kt < 2; ++kt) {
            float tmp[8];
            #pragma unroll
            for (int i = 0; i < 8; ++i) tmp[i] = W1[(kt*32 + g*8 + i) * Hsz + n];
            split8(tmp, w1h[nt][kt], w1l[nt][kt]);
        }
    }
    bf16x8 w2h[4], w2l[4];
    {
        const int n = w*16 + c;
        #pragma unroll
        for (int kt = 0; kt < 4; ++kt) {
            float tmp[8];
            #pragma unroll
            for (int i = 0; i < 8; ++i) tmp[i] = W2[(kt*32 + g*8 + i) * Dsz + n];
            split8(tmp, w2h[kt], w2l[kt]);
        }
    }
    const float b1r[2] = { b1[w*32 + c], b1[w*32 + 16 + c] };
    const float b2r    = b2[w*16 + c];

    // ---- loop-invariant swizzled LDS byte offsets ----
    int zwr[4], awr[2][4];
    #pragma unroll
    for (int reg = 0; reg < 4; ++reg) {
        const int row = 4*g + reg;
        zwr[reg] = (row*128 + (w*16 + c)*2) ^ ((row & 7) << 4);
        #pragma unroll
        for (int nt = 0; nt < 2; ++nt)
            awr[nt][reg] = (row*256 + (w*32 + nt*16 + c)*2) ^ ((row & 7) << 4);
    }
    int zrd[2], ard[4];
    #pragma unroll
    for (int kt = 0; kt < 2; ++kt) zrd[kt] = (c*128 + kt*64 + g*16) ^ ((c & 7) << 4);
    #pragma unroll
    for (int kt = 0; kt < 4; ++kt) ard[kt] = (c*256 + kt*64 + g*16) ^ ((c & 7) << 4);

    auto z_to_lds = [&]() {
        #pragma unroll
        for (int reg = 0; reg < 4; ++reg) {
            __hip_bfloat16 hb = __float2bfloat16(zreg[reg]);
            float hf = __bfloat162float(hb);
            stb16(zHs, zwr[reg], bf2u(hb));
            stb16(zLs, zwr[reg], bf2u(__float2bfloat16(zreg[reg] - hf)));
        }
    };

    z_to_lds();
    __syncthreads();

    const int n_steps = (int)ceilf(fabsf(ts[1] - ts[0]) / 0.05f);   // = 2 (exact in f32)

    for (int iv = 0; iv < Tsz - 1; ++iv) {
        const float h = (ts[iv + 1] - ts[iv]) / (float)n_steps;
        for (int s = 0; s < n_steps; ++s) {
            // ---- P1: layer 1 (frags straight from LDS, no repack) ----
            bf16x8 zh0 = ldb128(zHs, zrd[0]), zh1 = ldb128(zHs, zrd[1]);
            bf16x8 zl0 = ldb128(zLs, zrd[0]), zl1 = ldb128(zLs, zrd[1]);
            #pragma unroll
            for (int nt = 0; nt < 2; ++nt) {
                f32x4 acc = { b1r[nt], b1r[nt], b1r[nt], b1r[nt] };
                acc = MFMA(zh0, w1h[nt][0], acc);
                acc = MFMA(zh1, w1h[nt][1], acc);
                acc = MFMA(zh0, w1l[nt][0], acc);
                acc = MFMA(zh1, w1l[nt][1], acc);
                acc = MFMA(zl0, w1h[nt][0], acc);
                acc = MFMA(zl1, w1h[nt][1], acc);
                #pragma unroll
                for (int reg = 0; reg < 4; ++reg) {
                    float a = fast_tanh(acc[reg]);
                    __hip_bfloat16 hb = __float2bfloat16(a);
                    stb16(aHs, awr[nt][reg], bf2u(hb));
                    stb16(aLs, awr[nt][reg],
                          bf2u(__float2bfloat16(a - __bfloat162float(hb))));
                }
            }
            __syncthreads();
            // ---- P2: layer 2, two independent MFMA chains ----
            bf16x8 a0h = ldb128(aHs, ard[0]), a1h = ldb128(aHs, ard[1]);
            bf16x8 a2h = ldb128(aHs, ard[2]), a3h = ldb128(aHs, ard[3]);
            bf16x8 a0l = ldb128(aLs, ard[0]), a1l = ldb128(aLs, ard[1]);
            bf16x8 a2l = ldb128(aLs, ard[2]), a3l = ldb128(aLs, ard[3]);
            f32x4 accA = { b2r, b2r, b2r, b2r };
            f32x4 accB = { 0.f, 0.f, 0.f, 0.f };
            accA = MFMA(a0h, w2h[0], accA);  accB = MFMA(a2h, w2h[2], accB);
            accA = MFMA(a1h, w2h[1], accA);  accB = MFMA(a3h, w2h[3], accB);
            accA = MFMA(a0h, w2l[0], accA);  accB = MFMA(a2h, w2l[2], accB);
            accA = MFMA(a1h, w2l[1], accA);  accB = MFMA(a3h, w2l[3], accB);
            accA = MFMA(a0l, w2h[0], accA);  accB = MFMA(a2l, w2h[2], accB);
            accA = MFMA(a1l, w2h[1], accA);  accB = MFMA(a3l, w2h[3], accB);
            #pragma unroll
            for (int reg = 0; reg < 4; ++reg)
                zreg[reg] += h * (accA[reg] + accB[reg]);
            z_to_lds();                       // z for next substep
            __syncthreads();
        }
    }

    #pragma unroll
    for (int reg = 0; reg < 4; ++reg)
        out[(r0 + 4*g + reg) * Dsz + (w*16 + c)] = zreg[reg];
}

extern "C" void kernel_launch(void* const* d_in, const int* in_sizes, int n_in,
                              void* d_out, int out_size, void* d_ws, size_t ws_size,
                              hipStream_t stream) {
    const float* z0 = (const float*)d_in[0];
    const float* t  = (const float*)d_in[1];
    const float* W1 = (const float*)d_in[2];
    const float* b1 = (const float*)d_in[3];
    const float* W2 = (const float*)d_in[4];
    const float* b2 = (const float*)d_in[5];
    float* out = (float*)d_out;
    (void)in_sizes; (void)n_in; (void)out_size; (void)d_ws; (void)ws_size;

    ode_mfma3<<<dim3(Bsz / ROWS), dim3(NT), 0, stream>>>(z0, t, W1, b1, W2, b2, out);
}